// Round 13
// baseline (1014.657 us; speedup 1.0000x reference)
//
#include <hip/hip_runtime.h>

// Persistent-CG, full-row decomposition, versioned (virgin-line) buffers.
// R11 post-mortem (1002us, pred 800-1000 CONFIRMED): cached virgin-gen reads +
// no fences real. Residual ~14us/iter: exposed L3 first-touch in GEMM (depth-1
// prefetch too shallow), 2 gridbars + sc1 drain, r read-back + request queues.
// R12: (1) depth-2 column prefetch (covers L3 first-touch under 2 cols of
// compute; +48 VGPR live, ~170 total); (2) rst resident in LDS across iters
// (update writes rn into rst; deletes 272 global read-backs/iter); (3) r-publish
// vectorized to 68 float4 sc1 stores (shorter drain at barrier B). Arithmetic
// order byte-identical to R11. Barrier: R6/R8/R10-verified store-only, NO fence.

#define NN   4096
#define TT   17
#define PP   16
#define NTOT (NN*TT)          // 69632 floats/gen, 128B-aligned
#define NIT  47
#define NGEN 48
#define SLOTG (64*256)        // 16384 floats/gen
#define NBLK 256              // 1 block/CU, cooperative co-residency
#define NTHR 512              // 8 waves
#define EPB  272              // 17 cols x 16 own rows

// ws float offsets (all 128B aligned)
#define O_SSQ  0                        // [16][64] setup ssq partials (sc1 path)
#define O_BAR  1024                     // flags[256] + go replicas; 576 slots
#define O_SLOT 1600                     // [48 gens][64][256] dot slots
#define O_R    (O_SLOT + NGEN*SLOTG)    // [48 gens][NTOT] r

#define AGENT __HIP_MEMORY_SCOPE_AGENT
#define RLX   __ATOMIC_RELAXED

typedef float f32x4 __attribute__((ext_vector_type(4)));

__global__ void k_bzero(float* __restrict__ ws) {
    if (threadIdx.x < 576) ((unsigned*)(ws + O_BAR))[threadIdx.x] = 0u;
}

// Store-only monotonic grid barrier (R6/R8/R10-verified, NO exit fence).
__device__ __forceinline__ void gridbar(unsigned* bar, int phase, int b) {
    const unsigned target = (unsigned)(phase + 1);
    asm volatile("s_waitcnt vmcnt(0)" ::: "memory");   // sc1 stores drained
    __syncthreads();
    if (b == 0) {
        if (threadIdx.x >= 1 && threadIdx.x < NBLK) {
            while (__hip_atomic_load(&bar[threadIdx.x], RLX, AGENT) < target)
                __builtin_amdgcn_s_sleep(1);
        }
        __syncthreads();
        if (threadIdx.x < 8)
            __hip_atomic_store(&bar[256 + threadIdx.x*32], target, RLX, AGENT);
    } else {
        if (threadIdx.x == 0) {
            __hip_atomic_store(&bar[b], target, RLX, AGENT);
            while (__hip_atomic_load(&bar[256 + (b & 7)*32], RLX, AGENT) < target)
                __builtin_amdgcn_s_sleep(1);
        }
    }
    __syncthreads();
}

__global__ __launch_bounds__(NTHR, 2)
void k_cg(const float* __restrict__ Km, const float* __restrict__ yv,
          const float* __restrict__ Zm, const float* __restrict__ noise,
          float* __restrict__ out, float* __restrict__ ws) {
    __shared__ float4 p2a[8*TT*17];                  // wave partials rows 0-3
    __shared__ float4 p2b[8*TT*17];                  // rows 4-7 (pad 17)
    __shared__ __align__(16) float wq[8*TT*8];       // per-wave quarter sums
    __shared__ float rst[TT][16], wst[TT][16];       // own-row r (resident), w
    __shared__ float sm2[34][8], s_dg[34];
    __shared__ float s_scale[TT], s_rhs[TT], s_al[TT], s_be[TT], s_ap[TT], s_gp[TT];
    __shared__ float redd[TT];

    const int t = threadIdx.x, b = blockIdx.x;
    const int lane = t & 63, w = t >> 6;             // 8 waves
    const int h = t >> 8;                            // row-half 0/1 (8 rows each)
    const int kslot = t & 255;                       // 16 k-floats per thread
    unsigned* bar = (unsigned*)(ws + O_BAR);
    const float s2 = noise[0]*noise[0];
    int ph = 0;
    float pr = 0.f, sr = 0.f, xr = 0.f;              // per-thread CG state (t<272)

    // ---- one-time: K rows b*16+h*8+rr, k = g*1024 + kslot*4 -> 128 VGPRs ----
    float4 kreg[8][4];
    {
        const float* Kb = Km + (size_t)(b*16 + h*8)*NN + kslot*4;
        #pragma unroll
        for (int rr = 0; rr < 8; ++rr)
            #pragma unroll
            for (int g = 0; g < 4; ++g)
                kreg[rr][g] = *(const float4*)(Kb + (size_t)rr*NN + g*1024);
    }

    // ---- setup: per-column sum-of-squares partials (blocks 0..15) ----
    if (t < TT) redd[t] = 0.f;
    __syncthreads();
    if (b < 16 && t < 256) {
        int n = b*256 + t;
        float yy = yv[n];
        atomicAdd(&redd[0], yy*yy);
        #pragma unroll
        for (int j = 0; j < PP; ++j) { float v = Zm[n*PP + j]; atomicAdd(&redd[j+1], v*v); }
    }
    __syncthreads();
    if (b < 16 && t < TT)
        __hip_atomic_store(&ws[O_SSQ + b*64 + t], redd[t], RLX, AGENT);
    gridbar(bar, ph++, b);

    // ---- setup: scale/rhs replicated (sc1 reads); r gen-0 publish + rst ----
    if (t < TT) {
        float s = 0.f;
        #pragma unroll
        for (int i = 0; i < 16; ++i)
            s += __hip_atomic_load(&ws[O_SSQ + i*64 + t], RLX, AGENT);
        float scale, rh;
        if (t == 0) {
            rh = sqrtf(s); if (rh < 1e-10f) rh = 1.f;
            scale = 1.f/rh;
        } else {
            float zn = sqrtf(s);
            float bn = zn/(zn + 1e-10f);
            rh = (bn < 1e-10f) ? 1.f : bn;
            scale = 1.f/((zn + 1e-10f)*rh);
        }
        s_scale[t] = scale; s_rhs[t] = rh;
    }
    __syncthreads();
    if (t < EPB) {
        int c = t >> 4, i = t & 15, n = b*16 + i;
        float raw = (c == 0) ? yv[n] : Zm[n*PP + (c-1)];
        float r0 = raw * s_scale[c];
        rst[c][i] = r0;                              // resident own-row r
        __hip_atomic_store(&ws[O_R + c*NN + n], r0, RLX, AGENT);
    }
    gridbar(bar, ph++, b);

    // ---- 47 CG iterations ----
    for (int it = 0; it < NIT; ++it) {
        const float* rg = ws + O_R + it*NTOT;        // this iter's r generation
        const float* rcb = rg + kslot*4;

        // GEMM: direct-to-register, depth-2 column prefetch (virgin cached)
        float4 cu0 = *(const float4*)(rcb);
        float4 cu1 = *(const float4*)(rcb + 1024);
        float4 cu2 = *(const float4*)(rcb + 2048);
        float4 cu3 = *(const float4*)(rcb + 3072);
        const float* rn1 = rcb + NN;
        float4 nx0 = *(const float4*)(rn1);
        float4 nx1 = *(const float4*)(rn1 + 1024);
        float4 nx2 = *(const float4*)(rn1 + 2048);
        float4 nx3 = *(const float4*)(rn1 + 3072);
        #pragma unroll 1
        for (int c = 0; c < TT; ++c) {
            float4 f0, f1, f2, f3;
            if (c + 2 < TT) {
                const float* rn2 = rcb + (c+2)*NN;
                f0 = *(const float4*)(rn2);
                f1 = *(const float4*)(rn2 + 1024);
                f2 = *(const float4*)(rn2 + 2048);
                f3 = *(const float4*)(rn2 + 3072);
            }
            float acc[8];
            #pragma unroll
            for (int rr = 0; rr < 8; ++rr) acc[rr] = 0.f;
            #pragma unroll
            for (int rr = 0; rr < 8; ++rr)
                acc[rr] += kreg[rr][0].x*cu0.x + kreg[rr][0].y*cu0.y
                         + kreg[rr][0].z*cu0.z + kreg[rr][0].w*cu0.w;
            #pragma unroll
            for (int rr = 0; rr < 8; ++rr)
                acc[rr] += kreg[rr][1].x*cu1.x + kreg[rr][1].y*cu1.y
                         + kreg[rr][1].z*cu1.z + kreg[rr][1].w*cu1.w;
            #pragma unroll
            for (int rr = 0; rr < 8; ++rr)
                acc[rr] += kreg[rr][2].x*cu2.x + kreg[rr][2].y*cu2.y
                         + kreg[rr][2].z*cu2.z + kreg[rr][2].w*cu2.w;
            #pragma unroll
            for (int rr = 0; rr < 8; ++rr)
                acc[rr] += kreg[rr][3].x*cu3.x + kreg[rr][3].y*cu3.y
                         + kreg[rr][3].z*cu3.z + kreg[rr][3].w*cu3.w;
            // 2-stage butterfly: 64 lanes -> 16 lane-classes (order = R11)
            #pragma unroll
            for (int rr = 0; rr < 8; ++rr) {
                float v2 = acc[rr];
                v2 += __shfl_xor(v2, 32, 64);
                v2 += __shfl_xor(v2, 16, 64);
                acc[rr] = v2;
            }
            if (lane < 16) {
                p2a[(w*TT + c)*17 + lane] = make_float4(acc[0], acc[1], acc[2], acc[3]);
                p2b[(w*TT + c)*17 + lane] = make_float4(acc[4], acc[5], acc[6], acc[7]);
            }
            cu0 = nx0; cu1 = nx1; cu2 = nx2; cu3 = nx3;
            nx0 = f0;  nx1 = f1;  nx2 = f2;  nx3 = f3;
        }
        __syncthreads();                         // all waves' p2 writes visible

        // finish: (w2,c2) sums 16 lane-classes -> wq[w2][c2][0..7] (no atomics)
        if (t < 8*TT) {
            int w2 = t / TT, c2 = t % TT;
            float4 sa = make_float4(0.f,0.f,0.f,0.f), sb = make_float4(0.f,0.f,0.f,0.f);
            #pragma unroll
            for (int i = 0; i < 16; ++i) {
                float4 u = p2a[(w2*TT + c2)*17 + i];
                sa.x += u.x; sa.y += u.y; sa.z += u.z; sa.w += u.w;
                float4 v2 = p2b[(w2*TT + c2)*17 + i];
                sb.x += v2.x; sb.y += v2.y; sb.z += v2.z; sb.w += v2.w;
            }
            float* wr = &wq[(w2*TT + c2)*8];
            *(float4*)(wr)     = sa;
            *(float4*)(wr + 4) = sb;
        }
        __syncthreads();

        // assemble wst[c][i] = sum of 4 wave-quarters (deterministic order)
        if (t < EPB) {
            int c = t >> 4, i = t & 15, h2 = i >> 3, j = i & 7;
            float s = 0.f;
            #pragma unroll
            for (int q = 0; q < 4; ++q)
                s += wq[((h2*4 + q)*TT + c)*8 + j];
            wst[c][i] = s;
        }
        __syncthreads();

        // dp/gp fully local (rst resident): publish to THIS gen's slots via sc1
        if (t < TT) {
            float dp = 0.f, gp = 0.f;
            #pragma unroll
            for (int i = 0; i < 16; ++i) {
                float rv = rst[t][i];
                dp += rv * wst[t][i];
                gp += rv * rv;
            }
            float* sl = ws + O_SLOT + it*SLOTG;
            __hip_atomic_store(&sl[t*256 + b], dp, RLX, AGENT);
            __hip_atomic_store(&sl[(32 + t)*256 + b], gp, RLX, AGENT);
        }
        gridbar(bar, ph++, b);

        // phase B: slot reduce via CACHED float4 reads (virgin gen lines)
        if (t < 272) {
            int jdx = t >> 3, q = t & 7;
            int j = jdx + ((jdx >= 17) ? 15 : 0);   // 0..16 -> dp, 32..48 -> gp
            const float* sp = ws + O_SLOT + it*SLOTG + j*256 + q*32;
            float4 v0 = *(const float4*)(sp);
            float4 v1 = *(const float4*)(sp + 4);
            float4 v2 = *(const float4*)(sp + 8);
            float4 v3 = *(const float4*)(sp + 12);
            float4 v4 = *(const float4*)(sp + 16);
            float4 v5 = *(const float4*)(sp + 20);
            float4 v6 = *(const float4*)(sp + 24);
            float4 v7 = *(const float4*)(sp + 28);
            float sx = ((v0.x+v1.x)+(v2.x+v3.x)) + ((v4.x+v5.x)+(v6.x+v7.x));
            float sy = ((v0.y+v1.y)+(v2.y+v3.y)) + ((v4.y+v5.y)+(v6.y+v7.y));
            float sz = ((v0.z+v1.z)+(v2.z+v3.z)) + ((v4.z+v5.z)+(v6.z+v7.z));
            float sw = ((v0.w+v1.w)+(v2.w+v3.w)) + ((v4.w+v5.w)+(v6.w+v7.w));
            sm2[jdx][q] = (sx + sy) + (sz + sw);
        }
        __syncthreads();
        if (t < 34) {
            float g = 0.f;
            #pragma unroll
            for (int q = 0; q < 8; ++q) g += sm2[t][q];
            s_dg[t] = g;
        }
        __syncthreads();
        if (t < TT) {
            float del = s_dg[t], gam = s_dg[17 + t];
            float delta = del + s2*gam;          // r^T (K + s2 I) r
            float beta = 0.f, D = delta;
            if (it > 0) {
                float gpv = s_gp[t];
                beta = (fabsf(gpv) < 1e-30f) ? 0.f : gam/gpv;
                float apv = s_ap[t];
                D = delta - ((fabsf(apv) < 1e-30f) ? 0.f : beta*gam/apv);
            }
            float alpha = (fabsf(D) < 1e-30f) ? 0.f : gam/D;
            s_al[t] = alpha; s_be[t] = beta; s_ap[t] = alpha; s_gp[t] = gam;
        }
        __syncthreads();
        // update: pure-register; rn lands in resident rst (next iter's r)
        if (t < EPB) {
            int c = t >> 4, i = t & 15;
            float al = s_al[c], be = s_be[c];
            float rv = rst[c][i];
            float wv = wst[c][i] + s2*rv;
            pr = rv + be*pr;
            sr = wv + be*sr;
            xr = xr + al*pr;
            float rn = rv - al*sr;
            rst[c][i] = rn;
            if (it == NIT-1) out[(b*16 + i)*TT + c] = xr * s_rhs[c];
        }
        __syncthreads();
        // vectorized r-publish: 68 float4 sc1 stores from resident rst
        if (it < NIT-1 && t < 68) {
            int c = t >> 2, i4 = (t & 3) << 2;
            f32x4 v = { rst[c][i4], rst[c][i4+1], rst[c][i4+2], rst[c][i4+3] };
            float* dst = ws + O_R + (it+1)*NTOT + c*NN + b*16 + i4;
            asm volatile("global_store_dwordx4 %1, %0, off sc1"
                         :: "v"(v), "v"(dst) : "memory");
        }
        gridbar(bar, ph++, b);
    }
}

extern "C" void kernel_launch(void* const* d_in, const int* in_sizes, int n_in,
                              void* d_out, int out_size, void* d_ws, size_t ws_size,
                              hipStream_t stream) {
    const float* Km    = (const float*)d_in[0];
    const float* yv    = (const float*)d_in[1];
    const float* Zm    = (const float*)d_in[2];
    const float* noise = (const float*)d_in[3];
    float* out = (float*)d_out;
    float* ws  = (float*)d_ws;

    k_bzero<<<1, 576, 0, stream>>>(ws);
    void* args[] = {(void*)&Km, (void*)&yv, (void*)&Zm, (void*)&noise,
                    (void*)&out, (void*)&ws};
    (void)hipLaunchCooperativeKernel((const void*)k_cg, dim3(NBLK), dim3(NTHR),
                                     args, 0, stream);
}

// Round 14
// 933.563 us; speedup vs baseline: 1.0869x; 1.0869x over previous
//
#include <hip/hip_runtime.h>

// Persistent-CG, full-row decomposition, versioned buffers, PIPELINED CG.
// R13 post-mortem: R12 data-path tweaks null (1002->1015) => floor is sync
// structure: 2 gridbars/iter x ~3-4us + drains ~ 14us/iter vs 7.3us VALU.
// R14: Ghysels-style pipelined CG -- maintain W=A'r and z=A's by recurrence;
// GEMM computes n=A'W. Dot partials (gam=r.r, del=r.W, s2 term now inside W)
// and matvec input W publish together BEFORE one barrier -> 1 gridbar/iter
// (96 -> 49 total). Exact-arithmetic identical to the verified single-reduction
// recurrence; phase B drops the +s2*gam (W already includes it). Extra cost:
// one setup GEMM (W0=A'r0), register z, 1KB LDS (mst). All verified pieces
// unchanged: gridbar (store-only, no fence), virgin-gen cached reads, kreg
// layout, wq no-atomic finish, depth-2 prefetch. launch_bounds(512,1): LDS
// already forces 1 block/CU; lifts the 128-VGPR cap (no spill risk).

#define NN   4096
#define TT   17
#define PP   16
#define NTOT (NN*TT)          // 69632 floats/gen, 128B-aligned
#define NIT  47
#define NGEN 48
#define SLOTG (64*256)        // 16384 floats/gen
#define NBLK 256              // 1 block/CU, cooperative co-residency
#define NTHR 512              // 8 waves
#define EPB  272              // 17 cols x 16 own rows

// ws float offsets (all 128B aligned)
#define O_SSQ  0                        // [16][64] setup ssq partials (sc1 path)
#define O_BAR  1024                     // flags[256] + go replicas; 576 slots
#define O_SLOT 1600                     // [48 gens][64][256] dot slots
#define O_G    (O_SLOT + NGEN*SLOTG)    // [48 gens][NTOT] GEMM-input vectors

#define AGENT __HIP_MEMORY_SCOPE_AGENT
#define RLX   __ATOMIC_RELAXED

typedef float f32x4 __attribute__((ext_vector_type(4)));

__global__ void k_bzero(float* __restrict__ ws) {
    if (threadIdx.x < 576) ((unsigned*)(ws + O_BAR))[threadIdx.x] = 0u;
}

// Store-only monotonic grid barrier (R6/R8/R10-verified, NO exit fence).
__device__ __forceinline__ void gridbar(unsigned* bar, int phase, int b) {
    const unsigned target = (unsigned)(phase + 1);
    asm volatile("s_waitcnt vmcnt(0)" ::: "memory");   // sc1 stores drained
    __syncthreads();
    if (b == 0) {
        if (threadIdx.x >= 1 && threadIdx.x < NBLK) {
            while (__hip_atomic_load(&bar[threadIdx.x], RLX, AGENT) < target)
                __builtin_amdgcn_s_sleep(1);
        }
        __syncthreads();
        if (threadIdx.x < 8)
            __hip_atomic_store(&bar[256 + threadIdx.x*32], target, RLX, AGENT);
    } else {
        if (threadIdx.x == 0) {
            __hip_atomic_store(&bar[b], target, RLX, AGENT);
            while (__hip_atomic_load(&bar[256 + (b & 7)*32], RLX, AGENT) < target)
                __builtin_amdgcn_s_sleep(1);
        }
    }
    __syncthreads();
}

__global__ __launch_bounds__(NTHR, 1)
void k_cg(const float* __restrict__ Km, const float* __restrict__ yv,
          const float* __restrict__ Zm, const float* __restrict__ noise,
          float* __restrict__ out, float* __restrict__ ws) {
    __shared__ float4 p2a[8*TT*17];                  // wave partials rows 0-3
    __shared__ float4 p2b[8*TT*17];                  // rows 4-7 (pad 17)
    __shared__ __align__(16) float wq[8*TT*8];       // per-wave quarter sums
    __shared__ float rst[TT][16], Wst[TT][16], mst[TT][16];
    __shared__ float sm2[34][8], s_dg[34];
    __shared__ float s_scale[TT], s_rhs[TT], s_al[TT], s_be[TT], s_ap[TT], s_gp[TT];
    __shared__ float redd[TT];

    const int t = threadIdx.x, b = blockIdx.x;
    const int lane = t & 63, w = t >> 6;             // 8 waves
    const int h = t >> 8;                            // row-half 0/1 (8 rows each)
    const int kslot = t & 255;                       // 16 k-floats per thread
    unsigned* bar = (unsigned*)(ws + O_BAR);
    const float s2 = noise[0]*noise[0];
    int ph = 0;
    float pr = 0.f, sr = 0.f, zr = 0.f, xr = 0.f;    // per-thread CG state (t<272)

    // ---- one-time: K rows b*16+h*8+rr, k = g*1024 + kslot*4 -> 128 VGPRs ----
    float4 kreg[8][4];
    {
        const float* Kb = Km + (size_t)(b*16 + h*8)*NN + kslot*4;
        #pragma unroll
        for (int rr = 0; rr < 8; ++rr)
            #pragma unroll
            for (int g = 0; g < 4; ++g)
                kreg[rr][g] = *(const float4*)(Kb + (size_t)rr*NN + g*1024);
    }

    // full matvec on a published gen: mst[c][i] = (K * gin)[own rows]
    auto do_gemm = [&](const float* rg) {
        const float* rcb = rg + kslot*4;
        float4 cu0 = *(const float4*)(rcb);
        float4 cu1 = *(const float4*)(rcb + 1024);
        float4 cu2 = *(const float4*)(rcb + 2048);
        float4 cu3 = *(const float4*)(rcb + 3072);
        const float* rn1 = rcb + NN;
        float4 nx0 = *(const float4*)(rn1);
        float4 nx1 = *(const float4*)(rn1 + 1024);
        float4 nx2 = *(const float4*)(rn1 + 2048);
        float4 nx3 = *(const float4*)(rn1 + 3072);
        #pragma unroll 1
        for (int c = 0; c < TT; ++c) {
            float4 f0, f1, f2, f3;
            if (c + 2 < TT) {
                const float* rn2 = rcb + (c+2)*NN;
                f0 = *(const float4*)(rn2);
                f1 = *(const float4*)(rn2 + 1024);
                f2 = *(const float4*)(rn2 + 2048);
                f3 = *(const float4*)(rn2 + 3072);
            }
            float acc[8];
            #pragma unroll
            for (int rr = 0; rr < 8; ++rr) acc[rr] = 0.f;
            #pragma unroll
            for (int rr = 0; rr < 8; ++rr)
                acc[rr] += kreg[rr][0].x*cu0.x + kreg[rr][0].y*cu0.y
                         + kreg[rr][0].z*cu0.z + kreg[rr][0].w*cu0.w;
            #pragma unroll
            for (int rr = 0; rr < 8; ++rr)
                acc[rr] += kreg[rr][1].x*cu1.x + kreg[rr][1].y*cu1.y
                         + kreg[rr][1].z*cu1.z + kreg[rr][1].w*cu1.w;
            #pragma unroll
            for (int rr = 0; rr < 8; ++rr)
                acc[rr] += kreg[rr][2].x*cu2.x + kreg[rr][2].y*cu2.y
                         + kreg[rr][2].z*cu2.z + kreg[rr][2].w*cu2.w;
            #pragma unroll
            for (int rr = 0; rr < 8; ++rr)
                acc[rr] += kreg[rr][3].x*cu3.x + kreg[rr][3].y*cu3.y
                         + kreg[rr][3].z*cu3.z + kreg[rr][3].w*cu3.w;
            #pragma unroll
            for (int rr = 0; rr < 8; ++rr) {
                float v2 = acc[rr];
                v2 += __shfl_xor(v2, 32, 64);
                v2 += __shfl_xor(v2, 16, 64);
                acc[rr] = v2;
            }
            if (lane < 16) {
                p2a[(w*TT + c)*17 + lane] = make_float4(acc[0], acc[1], acc[2], acc[3]);
                p2b[(w*TT + c)*17 + lane] = make_float4(acc[4], acc[5], acc[6], acc[7]);
            }
            cu0 = nx0; cu1 = nx1; cu2 = nx2; cu3 = nx3;
            nx0 = f0;  nx1 = f1;  nx2 = f2;  nx3 = f3;
        }
        __syncthreads();
        if (t < 8*TT) {                  // sum 16 lane-classes (no atomics)
            int w2 = t / TT, c2 = t % TT;
            float4 sa = make_float4(0.f,0.f,0.f,0.f), sb = make_float4(0.f,0.f,0.f,0.f);
            #pragma unroll
            for (int i = 0; i < 16; ++i) {
                float4 u = p2a[(w2*TT + c2)*17 + i];
                sa.x += u.x; sa.y += u.y; sa.z += u.z; sa.w += u.w;
                float4 v2 = p2b[(w2*TT + c2)*17 + i];
                sb.x += v2.x; sb.y += v2.y; sb.z += v2.z; sb.w += v2.w;
            }
            float* wr = &wq[(w2*TT + c2)*8];
            *(float4*)(wr)     = sa;
            *(float4*)(wr + 4) = sb;
        }
        __syncthreads();
        if (t < EPB) {                   // assemble 4 wave-quarters -> mst
            int c = t >> 4, i = t & 15, h2 = i >> 3, j = i & 7;
            float s = 0.f;
            #pragma unroll
            for (int q = 0; q < 4; ++q)
                s += wq[((h2*4 + q)*TT + c)*8 + j];
            mst[c][i] = s;
        }
        __syncthreads();
    };

    // ---- setup: per-column sum-of-squares partials (blocks 0..15) ----
    if (t < TT) redd[t] = 0.f;
    __syncthreads();
    if (b < 16 && t < 256) {
        int n = b*256 + t;
        float yy = yv[n];
        atomicAdd(&redd[0], yy*yy);
        #pragma unroll
        for (int j = 0; j < PP; ++j) { float v = Zm[n*PP + j]; atomicAdd(&redd[j+1], v*v); }
    }
    __syncthreads();
    if (b < 16 && t < TT)
        __hip_atomic_store(&ws[O_SSQ + b*64 + t], redd[t], RLX, AGENT);
    gridbar(bar, ph++, b);

    // ---- setup: scale/rhs replicated; r0 -> rst + gen 0 publish ----
    if (t < TT) {
        float s = 0.f;
        #pragma unroll
        for (int i = 0; i < 16; ++i)
            s += __hip_atomic_load(&ws[O_SSQ + i*64 + t], RLX, AGENT);
        float scale, rh;
        if (t == 0) {
            rh = sqrtf(s); if (rh < 1e-10f) rh = 1.f;
            scale = 1.f/rh;
        } else {
            float zn = sqrtf(s);
            float bn = zn/(zn + 1e-10f);
            rh = (bn < 1e-10f) ? 1.f : bn;
            scale = 1.f/((zn + 1e-10f)*rh);
        }
        s_scale[t] = scale; s_rhs[t] = rh;
    }
    __syncthreads();
    if (t < EPB) {
        int c = t >> 4, i = t & 15, n = b*16 + i;
        float raw = (c == 0) ? yv[n] : Zm[n*PP + (c-1)];
        float r0 = raw * s_scale[c];
        rst[c][i] = r0;
        __hip_atomic_store(&ws[O_G + c*NN + n], r0, RLX, AGENT);
    }
    gridbar(bar, ph++, b);

    // ---- stage 0: W0 = K*r0 + s2*r0; slots[0]; publish W0 -> gen 1 ----
    do_gemm(ws + O_G);
    if (t < EPB) {
        int c = t >> 4, i = t & 15;
        Wst[c][i] = mst[c][i] + s2*rst[c][i];
    }
    __syncthreads();
    if (t < TT) {
        float dp = 0.f, gp = 0.f;
        #pragma unroll
        for (int i = 0; i < 16; ++i) {
            float rv = rst[t][i];
            dp += rv * Wst[t][i];
            gp += rv * rv;
        }
        float* sl = ws + O_SLOT;
        __hip_atomic_store(&sl[t*256 + b], dp, RLX, AGENT);
        __hip_atomic_store(&sl[(32 + t)*256 + b], gp, RLX, AGENT);
    }
    if (t < 68) {
        int c = t >> 2, i4 = (t & 3) << 2;
        f32x4 v = { Wst[c][i4], Wst[c][i4+1], Wst[c][i4+2], Wst[c][i4+3] };
        float* dst = ws + O_G + NTOT + c*NN + b*16 + i4;
        asm volatile("global_store_dwordx4 %1, %0, off sc1"
                     :: "v"(v), "v"(dst) : "memory");
    }

    // ---- 47 pipelined-CG iterations, ONE gridbar each ----
    for (int it = 0; it < NIT; ++it) {
        gridbar(bar, ph++, b);                       // gen it+1 + slots it ready

        do_gemm(ws + O_G + (size_t)(it+1)*NTOT);     // m = K * W_it (own rows)

        // slot reduce (gen it) via cached float4 reads of virgin lines
        if (t < 272) {
            int jdx = t >> 3, q = t & 7;
            int j = jdx + ((jdx >= 17) ? 15 : 0);    // 0..16 dp, 32..48 gp
            const float* sp = ws + O_SLOT + (size_t)it*SLOTG + j*256 + q*32;
            float4 v0 = *(const float4*)(sp);
            float4 v1 = *(const float4*)(sp + 4);
            float4 v2 = *(const float4*)(sp + 8);
            float4 v3 = *(const float4*)(sp + 12);
            float4 v4 = *(const float4*)(sp + 16);
            float4 v5 = *(const float4*)(sp + 20);
            float4 v6 = *(const float4*)(sp + 24);
            float4 v7 = *(const float4*)(sp + 28);
            float sx = ((v0.x+v1.x)+(v2.x+v3.x)) + ((v4.x+v5.x)+(v6.x+v7.x));
            float sy = ((v0.y+v1.y)+(v2.y+v3.y)) + ((v4.y+v5.y)+(v6.y+v7.y));
            float sz = ((v0.z+v1.z)+(v2.z+v3.z)) + ((v4.z+v5.z)+(v6.z+v7.z));
            float sw = ((v0.w+v1.w)+(v2.w+v3.w)) + ((v4.w+v5.w)+(v6.w+v7.w));
            sm2[jdx][q] = (sx + sy) + (sz + sw);
        }
        __syncthreads();
        if (t < 34) {
            float g = 0.f;
            #pragma unroll
            for (int q = 0; q < 8; ++q) g += sm2[t][q];
            s_dg[t] = g;
        }
        __syncthreads();
        if (t < TT) {
            float delta = s_dg[t], gam = s_dg[17 + t];   // delta = r.(A'r) full
            float beta = 0.f, D = delta;
            if (it > 0) {
                float gpv = s_gp[t];
                beta = (fabsf(gpv) < 1e-30f) ? 0.f : gam/gpv;
                float apv = s_ap[t];
                D = delta - ((fabsf(apv) < 1e-30f) ? 0.f : beta*gam/apv);
            }
            float alpha = (fabsf(D) < 1e-30f) ? 0.f : gam/D;
            s_al[t] = alpha; s_be[t] = beta; s_ap[t] = alpha; s_gp[t] = gam;
        }
        __syncthreads();
        // update own rows: p,s,z regs + r,W in LDS; n = A'W = m + s2*W
        if (t < EPB) {
            int c = t >> 4, i = t & 15;
            float al = s_al[c], be = s_be[c];
            float rv = rst[c][i], Wv = Wst[c][i];
            float nv = mst[c][i] + s2*Wv;
            pr = rv + be*pr;
            sr = Wv + be*sr;
            zr = nv + be*zr;
            xr = xr + al*pr;
            float rn = rv - al*sr;
            float Wn = Wv - al*zr;
            rst[c][i] = rn; Wst[c][i] = Wn;
            if (it == NIT-1) out[(b*16 + i)*TT + c] = xr * s_rhs[c];
        }
        __syncthreads();
        // publish next gen (W_{it+1}) + slots[it+1]; next gridbar drains
        if (it < NIT-1) {
            if (t < 68) {
                int c = t >> 2, i4 = (t & 3) << 2;
                f32x4 v = { Wst[c][i4], Wst[c][i4+1], Wst[c][i4+2], Wst[c][i4+3] };
                float* dst = ws + O_G + (size_t)(it+2)*NTOT + c*NN + b*16 + i4;
                asm volatile("global_store_dwordx4 %1, %0, off sc1"
                             :: "v"(v), "v"(dst) : "memory");
            }
            if (t < TT) {
                float dp = 0.f, gp = 0.f;
                #pragma unroll
                for (int i = 0; i < 16; ++i) {
                    float rv = rst[t][i];
                    dp += rv * Wst[t][i];
                    gp += rv * rv;
                }
                float* sl = ws + O_SLOT + (size_t)(it+1)*SLOTG;
                __hip_atomic_store(&sl[t*256 + b], dp, RLX, AGENT);
                __hip_atomic_store(&sl[(32 + t)*256 + b], gp, RLX, AGENT);
            }
        }
    }
}

extern "C" void kernel_launch(void* const* d_in, const int* in_sizes, int n_in,
                              void* d_out, int out_size, void* d_ws, size_t ws_size,
                              hipStream_t stream) {
    const float* Km    = (const float*)d_in[0];
    const float* yv    = (const float*)d_in[1];
    const float* Zm    = (const float*)d_in[2];
    const float* noise = (const float*)d_in[3];
    float* out = (float*)d_out;
    float* ws  = (float*)d_ws;

    k_bzero<<<1, 576, 0, stream>>>(ws);
    void* args[] = {(void*)&Km, (void*)&yv, (void*)&Zm, (void*)&noise,
                    (void*)&out, (void*)&ws};
    (void)hipLaunchCooperativeKernel((const void*)k_cg, dim3(NBLK), dim3(NTHR),
                                     args, 0, stream);
}